// Round 1
// baseline (23.680 us; speedup 1.0000x reference)
//
#include <hip/hip_runtime.h>
#include <math.h>

#define N_BINS 360
#define VEC4_PER_ROW 90   // 360/4

// Gaussian-vs-pred squared error, partial sums per block.
__global__ void __launch_bounds__(256) emd_partial_kernel(
    const float* __restrict__ y_pred,
    const int*   __restrict__ y_labels,
    float*       __restrict__ partials,
    int total_vec4)
{
    const float norm   = 0.07978845608028654f;  // 1/(sqrt(2*pi)*5)
    const float inv2s2 = 0.02f;                 // 1/(2*sigma^2), sigma=5

    float acc = 0.0f;
    const int stride = gridDim.x * blockDim.x;
    const float4* __restrict__ pred4 = reinterpret_cast<const float4*>(y_pred);

    for (int f = blockIdx.x * blockDim.x + threadIdx.x; f < total_vec4; f += stride) {
        const int row = f / VEC4_PER_ROW;                 // magic-number div by compiler
        const int b0  = (f - row * VEC4_PER_ROW) * 4;     // starting bin of this float4
        const float lbl = (float)y_labels[row];

        const float4 p = pred4[f];
        float pv[4] = {p.x, p.y, p.z, p.w};
        #pragma unroll
        for (int j = 0; j < 4; ++j) {
            const float t = (float)(b0 + j) - lbl;
            const float e = __expf(-t * t * inv2s2) * norm;  // v_exp_f32 path
            const float d = e - pv[j];
            acc = fmaf(d, d, acc);
        }
    }

    // wave (64-lane) butterfly reduce
    #pragma unroll
    for (int off = 32; off > 0; off >>= 1)
        acc += __shfl_down(acc, off, 64);

    __shared__ float wsum[4];  // 256 threads / 64 lanes
    const int wave = threadIdx.x >> 6;
    const int lane = threadIdx.x & 63;
    if (lane == 0) wsum[wave] = acc;
    __syncthreads();
    if (threadIdx.x == 0)
        partials[blockIdx.x] = wsum[0] + wsum[1] + wsum[2] + wsum[3];
}

// Deterministic final reduce: one block, f64 accumulate, scale by 1/B.
__global__ void __launch_bounds__(256) emd_final_kernel(
    const float* __restrict__ partials,
    int n,
    float* __restrict__ out,
    double invB)
{
    double acc = 0.0;
    for (int i = threadIdx.x; i < n; i += blockDim.x)
        acc += (double)partials[i];

    __shared__ double sd[256];
    sd[threadIdx.x] = acc;
    __syncthreads();
    #pragma unroll
    for (int s = 128; s > 0; s >>= 1) {
        if (threadIdx.x < s) sd[threadIdx.x] += sd[threadIdx.x + s];
        __syncthreads();
    }
    if (threadIdx.x == 0)
        out[0] = (float)(sd[0] * invB);
}

extern "C" void kernel_launch(void* const* d_in, const int* in_sizes, int n_in,
                              void* d_out, int out_size, void* d_ws, size_t ws_size,
                              hipStream_t stream)
{
    const float* y_pred   = (const float*)d_in[0];
    const int*   y_labels = (const int*)d_in[1];
    float* out = (float*)d_out;

    const int B = in_sizes[1];                 // 65536
    const int total_vec4 = B * VEC4_PER_ROW;   // 5,898,240

    float* partials = (float*)d_ws;

    const int block = 256;
    int grid = (total_vec4 + block - 1) / block;
    if (grid > 2048) grid = 2048;

    emd_partial_kernel<<<grid, block, 0, stream>>>(y_pred, y_labels, partials, total_vec4);
    emd_final_kernel<<<1, block, 0, stream>>>(partials, grid, out, 1.0 / (double)B);
}